// Round 5
// baseline (280.702 us; speedup 1.0000x reference)
//
#include <hip/hip_runtime.h>

// LinearLIFBlock: cur = X[16384x1024] * W^T[1024x1024]; LIF scan over t (64 steps).
// R5: double-buffered LDS K-loop (prefetch tile k+1 after the barrier, compute
// tile k -> load latency fully overlapped, ONE barrier/iter) + XOR chunk swizzle
// on the LDS layout (2-way banks = free, was 8-way). 128x256 block tile, grid=512
// (2 blocks/CU), wave-tile 64x128. A rows remapped to (b*64+t); in-register LIF
// via shfl relay. 3-term bf16 split, single K=3072 loop; margin-flagged columns
// (|h-1|<1.5e-4) get exact fp64 fixup.

#define T_DIM 64
#define B_DIM 256
#define F_DIM 1024
#define K_DIM 1024
#define M_DIM 16384            // T*B
#define COLS  (B_DIM * F_DIM)  // 262144 scan columns
#define KP    2048             // packed K: [hi | lo]
#define MARGIN 1.5e-4f
#define LIST_CAP 32768

typedef __attribute__((ext_vector_type(8))) short short8;
typedef __attribute__((ext_vector_type(4))) float floatx4;

#define ASYNC_CP16(gp, lp)                                                     \
    __builtin_amdgcn_global_load_lds(                                          \
        (const __attribute__((address_space(1))) unsigned int*)(gp),           \
        (__attribute__((address_space(3))) unsigned int*)(lp), 16, 0, 0)

// ---------------------------------------------------------------- bf16 split
__device__ inline unsigned short f32_to_bf16_rne(float f) {
    unsigned int u = __builtin_bit_cast(unsigned int, f);
    unsigned int r = (u + 0x7FFFu + ((u >> 16) & 1u)) >> 16;
    return (unsigned short)r;
}
__device__ inline float bf16_to_f32(unsigned short h) {
    unsigned int u = ((unsigned int)h) << 16;
    return __builtin_bit_cast(float, u);
}

// Fused split: blocks [0,16384) do X (+row remap to b*64+t), [16384,17408) do W.
__global__ __launch_bounds__(256) void split_kernel(
    const float* __restrict__ x, const float* __restrict__ Wm,
    unsigned short* __restrict__ A, unsigned short* __restrict__ B,
    unsigned int* __restrict__ counter)
{
    if (blockIdx.x == 0 && threadIdx.x == 0) *counter = 0;
    const int blk = blockIdx.x;
    const float* in;
    unsigned short* dst;
    int g;
    int orow;
    if (blk < 16384) {
        g = blk * 256 + threadIdx.x;          // float4 index into x
        int e = g * 4;
        int row = e >> 10;                    // t*256 + b
        orow = ((row & 255) << 6) | (row >> 8);  // b*64 + t
        in = x; dst = A;
    } else {
        g = (blk - 16384) * 256 + threadIdx.x;
        int e = g * 4;
        orow = e >> 10;                       // o
        in = Wm; dst = B;
    }
    int k = (g * 4) & 1023;
    float4 v = reinterpret_cast<const float4*>(in)[g];
    ushort4 h, l;
    float f;
    f = v.x; h.x = f32_to_bf16_rne(f); l.x = f32_to_bf16_rne(f - bf16_to_f32(h.x));
    f = v.y; h.y = f32_to_bf16_rne(f); l.y = f32_to_bf16_rne(f - bf16_to_f32(h.y));
    f = v.z; h.z = f32_to_bf16_rne(f); l.z = f32_to_bf16_rne(f - bf16_to_f32(h.z));
    f = v.w; h.w = f32_to_bf16_rne(f); l.w = f32_to_bf16_rne(f - bf16_to_f32(h.w));
    reinterpret_cast<ushort4*>(dst)[(size_t)orow * (KP / 4) + (k >> 2)] = h;
    reinterpret_cast<ushort4*>(dst)[(size_t)orow * (KP / 4) + 256 + (k >> 2)] = l;
}

// ----------------------------------------------- fused MFMA GEMM + LIF scan
// Block tile 128(M) x 256(N); effective K=3072:
//   seg0 = A.hi*B.hi, seg1 = A.lo*B.hi, seg2 = A.hi*B.lo
__global__ __launch_bounds__(256, 2) void gemm_scan_kernel(
    const unsigned short* __restrict__ A,  // [16384][2048], rows b*64+t
    const unsigned short* __restrict__ B,  // [1024][2048],  rows o
    float* __restrict__ out,
    unsigned int* __restrict__ counter, unsigned int* __restrict__ list)
{
    __shared__ unsigned short As[2][128 * 32];  // 2 x 8 KB
    __shared__ unsigned short Bs[2][256 * 32];  // 2 x 16 KB

    const int tid  = threadIdx.x;
    const int lane = tid & 63;
    const int wv   = tid >> 6;
    // XCD-aware: XCD = lid&7 owns a contiguous 16-mt stripe; nt varies fastest.
    const int lid = blockIdx.x;                      // 0..511
    const int mt  = ((lid & 7) << 4) | (lid >> 5);   // 0..127
    const int nt  = (lid >> 3) & 3;                  // 0..3
    const int m0  = mt * 128;
    const int n0  = nt * 256;
    const int wm  = (wv & 1) * 64;
    const int wn  = (wv >> 1) * 128;

    floatx4 acc[4][8] = {};

    const int srow = tid >> 2;                      // 0..63 staging row
    const int slin = (tid & 3) * 8;                 // linear LDS chunk (dest)
    const int ssw  = (((tid & 3) ^ ((tid >> 3) & 3)) * 8);  // swizzled global chunk (src)
    const int lrow = lane & 15;
    const int q    = lane >> 4;                     // 0..3
    const int rsw  = ((lrow >> 1) & 3);             // read-side swizzle key

    const unsigned short* Ab = A + (size_t)m0 * KP;
    const unsigned short* Bb = B + (size_t)n0 * KP;

#define STAGE(p, aoff, boff)                                                   \
    do {                                                                       \
        ASYNC_CP16(Ab + (size_t)srow * KP + (aoff) + ssw,                      \
                   As[p] + srow * 32 + slin);                                  \
        ASYNC_CP16(Ab + (size_t)(srow + 64) * KP + (aoff) + ssw,               \
                   As[p] + (srow + 64) * 32 + slin);                           \
        ASYNC_CP16(Bb + (size_t)srow * KP + (boff) + ssw,                      \
                   Bs[p] + srow * 32 + slin);                                  \
        ASYNC_CP16(Bb + (size_t)(srow + 64) * KP + (boff) + ssw,               \
                   Bs[p] + (srow + 64) * 32 + slin);                           \
        ASYNC_CP16(Bb + (size_t)(srow + 128) * KP + (boff) + ssw,              \
                   Bs[p] + (srow + 128) * 32 + slin);                          \
        ASYNC_CP16(Bb + (size_t)(srow + 192) * KP + (boff) + ssw,              \
                   Bs[p] + (srow + 192) * 32 + slin);                          \
    } while (0)

    // prologue: stage k=0 into buffer 0
    STAGE(0, 0, 0);

    int p = 0;
    for (int it = 0; it < 96; ++it) {
        // Barrier drains the prefetch into buf p (overlapped with prev compute)
        // and guarantees all waves finished reading buf 1-p.
        __syncthreads();
        if (it + 1 < 96) {
            const int k1 = (it + 1) * 32;
            const int aoff1 = (k1 < 2048) ? k1 : k1 - 2048;  // seg2 replays hi
            const int boff1 = (k1 < 1024) ? k1 : k1 - 1024;  // seg1/2 replay
            STAGE(1 - p, aoff1, boff1);
        }

        short8 a[4], b[8];
#pragma unroll
        for (int i = 0; i < 4; ++i)
            a[i] = *reinterpret_cast<const short8*>(
                &As[p][(wm + i * 16 + lrow) * 32 + (q ^ rsw) * 8]);
#pragma unroll
        for (int j = 0; j < 8; ++j)
            b[j] = *reinterpret_cast<const short8*>(
                &Bs[p][(wn + j * 16 + lrow) * 32 + (q ^ rsw) * 8]);
#pragma unroll
        for (int i = 0; i < 4; ++i)
#pragma unroll
            for (int j = 0; j < 8; ++j)
                acc[i][j] = __builtin_amdgcn_mfma_f32_16x16x32_bf16(a[i], b[j], acc[i][j], 0, 0, 0);
        p ^= 1;
    }
#undef STAGE

    // ---- fused LIF scan in registers (validated relay) ----
    // Wave owns all 64 t of batch b = mt*2 + (wv&1), cols o = n0+wn+j*16+col.
    // acc[i][j][r] = cur at t = i*16 + q*4 + r, col = lane&15.
    const int col = lane & 15;
    const int b_g = mt * 2 + (wv & 1);

    unsigned int fmask = 0;
#pragma unroll
    for (int j = 0; j < 8; ++j) {
        float v = 0.f;
        bool fl = false;
#pragma unroll
        for (int i = 0; i < 4; ++i) {
#pragma unroll
            for (int qq = 0; qq < 4; ++qq) {
                if (q == qq) {
#pragma unroll
                    for (int r = 0; r < 4; ++r) {
                        float cu = acc[i][j][r];
                        float h = v + (cu - v) * 0.5f;
                        float d = h - 1.0f;
                        bool sp = (d >= 0.f);
                        fl |= (fabsf(d) < MARGIN);
                        acc[i][j][r] = sp ? 1.0f : 0.0f;  // spike overwrites cur
                        v = sp ? 0.f : h;
                    }
                }
                v = __shfl(v, qq * 16 + col, 64);  // broadcast owner's v
            }
        }
        if (fl) fmask |= (1u << j);
    }
    fmask |= __shfl_xor(fmask, 16, 64);
    fmask |= __shfl_xor(fmask, 32, 64);

    // spike stores
    float* outp = out + (size_t)b_g * F_DIM;
#pragma unroll
    for (int i = 0; i < 4; ++i)
#pragma unroll
        for (int j = 0; j < 8; ++j)
#pragma unroll
            for (int r = 0; r < 4; ++r) {
                int t = i * 16 + q * 4 + r;
                int o = n0 + wn + j * 16 + col;
                outp[(size_t)t * COLS + o] = acc[i][j][r];
            }

    if (q == 0 && fmask) {
        for (int j = 0; j < 8; ++j)
            if (fmask & (1u << j)) {
                unsigned int idx = atomicAdd(counter, 1u);
                if (idx < LIST_CAP)
                    list[idx] = (unsigned int)(b_g * F_DIM + n0 + wn + j * 16 + col);
            }
    }
}

// ------------------------------------------------------- exact fp64 fixup
__global__ __launch_bounds__(256) void fixup_kernel(
    const float* __restrict__ x, const float* __restrict__ W,
    const unsigned int* __restrict__ counter, const unsigned int* __restrict__ list,
    float* __restrict__ out)
{
    __shared__ double curd[T_DIM];
    __shared__ float wrow[K_DIM];
    unsigned int n = *counter;
    if (n > LIST_CAP) n = LIST_CAP;
    const int wv = threadIdx.x >> 6, lane = threadIdx.x & 63;

    for (unsigned int idx = blockIdx.x; idx < n; idx += gridDim.x) {
        const unsigned int c = list[idx];
        const int b = c >> 10, o = c & 1023;
        __syncthreads();
        for (int k = threadIdx.x; k < K_DIM; k += 256) wrow[k] = W[(size_t)o * K_DIM + k];
        __syncthreads();
        for (int it = 0; it < 16; ++it) {
            const int t = it * 4 + wv;
            const float* xp = x + (size_t)t * COLS + (size_t)b * F_DIM + lane * 16;
            const float* wp = wrow + lane * 16;
            double s = 0.0;
#pragma unroll
            for (int qq = 0; qq < 4; ++qq) {
                float4 xv = reinterpret_cast<const float4*>(xp)[qq];
                float4 wq = reinterpret_cast<const float4*>(wp)[qq];
                s += (double)xv.x * (double)wq.x + (double)xv.y * (double)wq.y +
                     (double)xv.z * (double)wq.z + (double)xv.w * (double)wq.w;
            }
#pragma unroll
            for (int off = 32; off > 0; off >>= 1) s += __shfl_down(s, off, 64);
            if (lane == 0) curd[t] = s;
        }
        __syncthreads();
        if (threadIdx.x == 0) {
            double v = 0.0;
            for (int t = 0; t < T_DIM; ++t) {
                double h = v + (curd[t] - v) * 0.5;
                bool s = (h >= 1.0);
                out[(size_t)t * COLS + c] = s ? 1.0f : 0.0f;
                v = s ? 0.0 : h;
            }
        }
        __syncthreads();
    }
}

// --------------------------------------------------- fp64 fallback (round-1)
#define TILE 64
#define KC 32
#define XS_LD 36
#define SC_LD 65

__global__ __launch_bounds__(256) void lif_fused_kernel(
    const float* __restrict__ x, const float* __restrict__ Wm, float* __restrict__ out)
{
    __shared__ __align__(16) unsigned char smem_raw[TILE * SC_LD * sizeof(double)];
    float* sf = reinterpret_cast<float*>(smem_raw);
    double* sd = reinterpret_cast<double*>(smem_raw);
    float* Xs = sf;
    float* Ws = sf + TILE * XS_LD;

    const int b = blockIdx.y;
    const int o0 = blockIdx.x * TILE;
    const int tid = threadIdx.x;
    const int tx = tid & 15, ty = tid >> 4;

    double acc[4][4];
#pragma unroll
    for (int i = 0; i < 4; ++i)
#pragma unroll
        for (int j = 0; j < 4; ++j) acc[i][j] = 0.0;

    const int r = tid >> 3, c4 = (tid & 7) * 4;
    const float* xbase = x + (size_t)b * F_DIM;

    for (int k0 = 0; k0 < K_DIM; k0 += KC) {
        __syncthreads();
        float4 xv0 = *reinterpret_cast<const float4*>(xbase + (size_t)r * COLS + k0 + c4);
        float4 xv1 = *reinterpret_cast<const float4*>(xbase + (size_t)(r + 32) * COLS + k0 + c4);
        *reinterpret_cast<float4*>(Xs + r * XS_LD + c4) = xv0;
        *reinterpret_cast<float4*>(Xs + (r + 32) * XS_LD + c4) = xv1;
        float4 wv0 = *reinterpret_cast<const float4*>(Wm + (size_t)(o0 + r) * K_DIM + k0 + c4);
        float4 wv1 = *reinterpret_cast<const float4*>(Wm + (size_t)(o0 + r + 32) * K_DIM + k0 + c4);
        *reinterpret_cast<float4*>(Ws + r * XS_LD + c4) = wv0;
        *reinterpret_cast<float4*>(Ws + (r + 32) * XS_LD + c4) = wv1;
        __syncthreads();
#pragma unroll 4
        for (int kk = 0; kk < KC; ++kk) {
            double xa[4], wb[4];
#pragma unroll
            for (int i = 0; i < 4; ++i) xa[i] = (double)Xs[(4 * ty + i) * XS_LD + kk];
#pragma unroll
            for (int j = 0; j < 4; ++j) wb[j] = (double)Ws[(4 * tx + j) * XS_LD + kk];
#pragma unroll
            for (int i = 0; i < 4; ++i)
#pragma unroll
                for (int j = 0; j < 4; ++j) acc[i][j] = fma(xa[i], wb[j], acc[i][j]);
        }
    }
    __syncthreads();
#pragma unroll
    for (int i = 0; i < 4; ++i)
#pragma unroll
        for (int j = 0; j < 4; ++j) sd[(4 * ty + i) * SC_LD + (4 * tx + j)] = acc[i][j];
    __syncthreads();
    if (tid < TILE) {
        double v = 0.0;
        float* outp = out + (size_t)b * F_DIM + o0 + tid;
        for (int t = 0; t < T_DIM; ++t) {
            double cu = sd[t * SC_LD + tid];
            double h = v + (cu - v) * 0.5;
            bool s = (h >= 1.0);
            outp[(size_t)t * COLS] = s ? 1.0f : 0.0f;
            v = s ? 0.0 : h;
        }
    }
}

// ------------------------------------------------------------------- launch
extern "C" void kernel_launch(void* const* d_in, const int* in_sizes, int n_in,
                              void* d_out, int out_size, void* d_ws, size_t ws_size,
                              hipStream_t stream) {
    const float* x = (const float*)d_in[0];   // [64][256][1024]
    const float* Wm = (const float*)d_in[1];  // [1024][1024]
    float* out = (float*)d_out;

    const size_t OFF_A   = 0;                                   // 64 MB
    const size_t OFF_B   = OFF_A + (size_t)M_DIM * KP * 2;      // 4 MB
    const size_t OFF_CNT = OFF_B + (size_t)F_DIM * KP * 2;
    const size_t OFF_LST = OFF_CNT + 256;
    const size_t NEEDED  = OFF_LST + (size_t)LIST_CAP * 4;

    if (ws_size < NEEDED) {
        dim3 grid(F_DIM / TILE, B_DIM, 1);
        lif_fused_kernel<<<grid, dim3(256), 0, stream>>>(x, Wm, out);
        return;
    }

    unsigned char* ws = (unsigned char*)d_ws;
    unsigned short* Abuf = (unsigned short*)(ws + OFF_A);
    unsigned short* Bbuf = (unsigned short*)(ws + OFF_B);
    unsigned int* counter = (unsigned int*)(ws + OFF_CNT);
    unsigned int* list = (unsigned int*)(ws + OFF_LST);

    split_kernel<<<dim3(16384 + 1024), dim3(256), 0, stream>>>(x, Wm, Abuf, Bbuf, counter);
    gemm_scan_kernel<<<dim3(512), dim3(256), 0, stream>>>(Abuf, Bbuf, out, counter, list);
    fixup_kernel<<<dim3(512), dim3(256), 0, stream>>>(x, Wm, counter, list, out);
}

// Round 6
// 272.911 us; speedup vs baseline: 1.0285x; 1.0285x over previous
//
#include <hip/hip_runtime.h>

// LinearLIFBlock: cur = X[16384x1024] * W^T[1024x1024]; LIF scan over t (64 steps).
// R6: back to the proven 2-barrier K-loop (R5's runtime-indexed dbuf defeated the
// compiler's LDS aliasing analysis). BK=64 staging (barriers 192->96, LDS 48 KB
// keeps 2 blocks/CU) + validated XOR source-side swizzle (bank conflicts = 0).
// fp64 fixup of margin-flagged columns (|h-1|<1.5e-4) fused into the block tail
// (overlaps other blocks' GEMM). 128x256 tile, grid=512, wave 64x128, A rows
// remapped to (b*64+t), in-register LIF shfl relay (validated R3/R4).

#define T_DIM 64
#define B_DIM 256
#define F_DIM 1024
#define K_DIM 1024
#define M_DIM 16384            // T*B
#define COLS  (B_DIM * F_DIM)  // 262144 scan columns
#define KP    2048             // packed K: [hi | lo]
#define MARGIN 1.5e-4f

typedef __attribute__((ext_vector_type(8))) short short8;
typedef __attribute__((ext_vector_type(4))) float floatx4;

#define ASYNC_CP16(gp, lp)                                                     \
    __builtin_amdgcn_global_load_lds(                                          \
        (const __attribute__((address_space(1))) unsigned int*)(gp),           \
        (__attribute__((address_space(3))) unsigned int*)(lp), 16, 0, 0)

// ---------------------------------------------------------------- bf16 split
__device__ inline unsigned short f32_to_bf16_rne(float f) {
    unsigned int u = __builtin_bit_cast(unsigned int, f);
    unsigned int r = (u + 0x7FFFu + ((u >> 16) & 1u)) >> 16;
    return (unsigned short)r;
}
__device__ inline float bf16_to_f32(unsigned short h) {
    unsigned int u = ((unsigned int)h) << 16;
    return __builtin_bit_cast(float, u);
}

// Fused split: blocks [0,16384) do X (+row remap to b*64+t), [16384,17408) do W.
__global__ __launch_bounds__(256) void split_kernel(
    const float* __restrict__ x, const float* __restrict__ Wm,
    unsigned short* __restrict__ A, unsigned short* __restrict__ B)
{
    const int blk = blockIdx.x;
    const float* in;
    unsigned short* dst;
    int g;
    int orow;
    if (blk < 16384) {
        g = blk * 256 + threadIdx.x;          // float4 index into x
        int e = g * 4;
        int row = e >> 10;                    // t*256 + b
        orow = ((row & 255) << 6) | (row >> 8);  // b*64 + t
        in = x; dst = A;
    } else {
        g = (blk - 16384) * 256 + threadIdx.x;
        int e = g * 4;
        orow = e >> 10;                       // o
        in = Wm; dst = B;
    }
    int k = (g * 4) & 1023;
    float4 v = reinterpret_cast<const float4*>(in)[g];
    ushort4 h, l;
    float f;
    f = v.x; h.x = f32_to_bf16_rne(f); l.x = f32_to_bf16_rne(f - bf16_to_f32(h.x));
    f = v.y; h.y = f32_to_bf16_rne(f); l.y = f32_to_bf16_rne(f - bf16_to_f32(h.y));
    f = v.z; h.z = f32_to_bf16_rne(f); l.z = f32_to_bf16_rne(f - bf16_to_f32(h.z));
    f = v.w; h.w = f32_to_bf16_rne(f); l.w = f32_to_bf16_rne(f - bf16_to_f32(h.w));
    reinterpret_cast<ushort4*>(dst)[(size_t)orow * (KP / 4) + (k >> 2)] = h;
    reinterpret_cast<ushort4*>(dst)[(size_t)orow * (KP / 4) + 256 + (k >> 2)] = l;
}

// -------------------------------- fused MFMA GEMM + LIF scan + fp64 fixup
// Block tile 128(M) x 256(N); effective K=3072:
//   seg0 = A.hi*B.hi, seg1 = A.lo*B.hi, seg2 = A.hi*B.lo
__global__ __launch_bounds__(256, 2) void gemm_scan_kernel(
    const unsigned short* __restrict__ A,  // [16384][2048], rows b*64+t
    const unsigned short* __restrict__ B,  // [1024][2048],  rows o
    const float* __restrict__ x,           // originals, for exact fixup
    const float* __restrict__ Wm,
    float* __restrict__ out)
{
    __shared__ unsigned short As[128 * 64];  // 16 KB (reused by fixup tail)
    __shared__ unsigned short Bs[256 * 64];  // 32 KB
    __shared__ unsigned int fl_cnt;

    const int tid  = threadIdx.x;
    const int lane = tid & 63;
    const int wv   = tid >> 6;
    // XCD-aware: XCD = lid&7 owns a contiguous 16-mt stripe; nt varies fastest.
    const int lid = blockIdx.x;                      // 0..511
    const int mt  = ((lid & 7) << 4) | (lid >> 5);   // 0..127
    const int nt  = (lid >> 3) & 3;                  // 0..3
    const int m0  = mt * 128;
    const int n0  = nt * 256;
    const int wm  = (wv & 1) * 64;
    const int wn  = (wv >> 1) * 128;

    floatx4 acc[4][8] = {};

    // staging: 8 chunks (16B) per 64-wide row; source-side XOR swizzle so the
    // LDS dest stays lane-linear (global_load_lds requirement).
    const int srow8 = tid >> 3;                     // 0..31
    const int c8    = tid & 7;                      // dest chunk slot
    const int csrc  = (c8 ^ (srow8 & 7)) * 8;       // swizzled source chunk (elems)
    const int lrow  = lane & 15;
    const int q     = lane >> 4;                    // 0..3
    const int key   = lrow & 7;                     // read-side swizzle key

    const unsigned short* Ab = A + (size_t)m0 * KP;
    const unsigned short* Bb = B + (size_t)n0 * KP;

    for (int it = 0; it < 48; ++it) {
        const int k0 = it * 64;
        const int aoff = (k0 < 2048) ? k0 : k0 - 2048;  // seg2 replays hi
        const int boff = (k0 < 1024) ? k0 : k0 - 1024;  // seg1/2 replay hi
        __syncthreads();  // prev iter's LDS reads done
#pragma unroll
        for (int p = 0; p < 4; ++p) {
            const int row = p * 32 + srow8;
            ASYNC_CP16(Ab + (size_t)row * KP + aoff + csrc, As + row * 64 + c8 * 8);
        }
#pragma unroll
        for (int p = 0; p < 8; ++p) {
            const int row = p * 32 + srow8;
            ASYNC_CP16(Bb + (size_t)row * KP + boff + csrc, Bs + row * 64 + c8 * 8);
        }
        __syncthreads();  // staging complete

#pragma unroll
        for (int s = 0; s < 2; ++s) {
            const int sl = ((s * 4 + q) ^ key) * 8;
            short8 a[4], b[8];
#pragma unroll
            for (int i = 0; i < 4; ++i)
                a[i] = *reinterpret_cast<const short8*>(&As[(wm + i * 16 + lrow) * 64 + sl]);
#pragma unroll
            for (int j = 0; j < 8; ++j)
                b[j] = *reinterpret_cast<const short8*>(&Bs[(wn + j * 16 + lrow) * 64 + sl]);
#pragma unroll
            for (int i = 0; i < 4; ++i)
#pragma unroll
                for (int j = 0; j < 8; ++j)
                    acc[i][j] = __builtin_amdgcn_mfma_f32_16x16x32_bf16(a[i], b[j], acc[i][j], 0, 0, 0);
        }
    }

    // ---- fused LIF scan in registers (validated relay) ----
    // Wave owns all 64 t of batch b = mt*2 + (wv&1), cols o = n0+wn+j*16+col.
    // acc[i][j][r] = cur at t = i*16 + q*4 + r, col = lane&15.
    const int col = lane & 15;
    const int b_g = mt * 2 + (wv & 1);

    unsigned int fmask = 0;
#pragma unroll
    for (int j = 0; j < 8; ++j) {
        float v = 0.f;
        bool fl = false;
#pragma unroll
        for (int i = 0; i < 4; ++i) {
#pragma unroll
            for (int qq = 0; qq < 4; ++qq) {
                if (q == qq) {
#pragma unroll
                    for (int r = 0; r < 4; ++r) {
                        float cu = acc[i][j][r];
                        float h = v + (cu - v) * 0.5f;
                        float d = h - 1.0f;
                        bool sp = (d >= 0.f);
                        fl |= (fabsf(d) < MARGIN);
                        acc[i][j][r] = sp ? 1.0f : 0.0f;  // spike overwrites cur
                        v = sp ? 0.f : h;
                    }
                }
                v = __shfl(v, qq * 16 + col, 64);  // broadcast owner's v
            }
        }
        if (fl) fmask |= (1u << j);
    }
    fmask |= __shfl_xor(fmask, 16, 64);
    fmask |= __shfl_xor(fmask, 32, 64);

    // spike stores
    float* outp = out + (size_t)b_g * F_DIM;
#pragma unroll
    for (int i = 0; i < 4; ++i)
#pragma unroll
        for (int j = 0; j < 8; ++j)
#pragma unroll
            for (int r = 0; r < 4; ++r) {
                int t = i * 16 + q * 4 + r;
                int o = n0 + wn + j * 16 + col;
                outp[(size_t)t * COLS + o] = acc[i][j][r];
            }

    // ---- in-block exact fp64 fixup of margin-flagged columns ----
    // LDS reuse over As (ushort offsets): curd 0..255 (64 doubles),
    // wrow 256..2303 (1024 floats), fl_list 2304..3327 (512 uints, = worst case).
    double* curd = reinterpret_cast<double*>(As);
    float* wrow = reinterpret_cast<float*>(As + 256);
    unsigned int* fl_list = reinterpret_cast<unsigned int*>(As + 2304);

    __syncthreads();  // all LDS reads of the GEMM done; safe to reuse As
    if (tid == 0) fl_cnt = 0;
    __syncthreads();
    if (q == 0 && fmask) {
        for (int j = 0; j < 8; ++j)
            if (fmask & (1u << j)) {
                unsigned int idx = atomicAdd(&fl_cnt, 1u);
                fl_list[idx] = (unsigned int)((b_g << 10) | (n0 + wn + j * 16 + col));
            }
    }
    __syncthreads();
    const unsigned int nfl = fl_cnt;

    for (unsigned int e = 0; e < nfl; ++e) {
        const unsigned int c = fl_list[e];
        const int bb = c >> 10, o = c & 1023;
        __syncthreads();  // guard wrow/curd reuse across entries
        for (int k = tid; k < K_DIM; k += 256) wrow[k] = Wm[(size_t)o * K_DIM + k];
        __syncthreads();
        for (int itt = 0; itt < 16; ++itt) {
            const int t = itt * 4 + wv;
            const float* xp = x + (size_t)t * COLS + (size_t)bb * F_DIM + lane * 16;
            double sacc = 0.0;
#pragma unroll
            for (int qq = 0; qq < 4; ++qq) {
                float4 xv = reinterpret_cast<const float4*>(xp)[qq];
                float4 wq = *reinterpret_cast<const float4*>(&wrow[lane * 16 + qq * 4]);
                sacc += (double)xv.x * (double)wq.x + (double)xv.y * (double)wq.y +
                        (double)xv.z * (double)wq.z + (double)xv.w * (double)wq.w;
            }
#pragma unroll
            for (int off = 32; off > 0; off >>= 1) sacc += __shfl_down(sacc, off, 64);
            if (lane == 0) curd[t] = sacc;
        }
        __syncthreads();
        if (tid == 0) {
            double v = 0.0;
            for (int t = 0; t < T_DIM; ++t) {
                double h = v + (curd[t] - v) * 0.5;
                bool sp = (h >= 1.0);
                out[(size_t)t * COLS + c] = sp ? 1.0f : 0.0f;
                v = sp ? 0.0 : h;
            }
        }
    }
}

// --------------------------------------------------- fp64 fallback (round-1)
#define TILE 64
#define KC 32
#define XS_LD 36
#define SC_LD 65

__global__ __launch_bounds__(256) void lif_fused_kernel(
    const float* __restrict__ x, const float* __restrict__ Wm, float* __restrict__ out)
{
    __shared__ __align__(16) unsigned char smem_raw[TILE * SC_LD * sizeof(double)];
    float* sf = reinterpret_cast<float*>(smem_raw);
    double* sd = reinterpret_cast<double*>(smem_raw);
    float* Xs = sf;
    float* Ws = sf + TILE * XS_LD;

    const int b = blockIdx.y;
    const int o0 = blockIdx.x * TILE;
    const int tid = threadIdx.x;
    const int tx = tid & 15, ty = tid >> 4;

    double acc[4][4];
#pragma unroll
    for (int i = 0; i < 4; ++i)
#pragma unroll
        for (int j = 0; j < 4; ++j) acc[i][j] = 0.0;

    const int r = tid >> 3, c4 = (tid & 7) * 4;
    const float* xbase = x + (size_t)b * F_DIM;

    for (int k0 = 0; k0 < K_DIM; k0 += KC) {
        __syncthreads();
        float4 xv0 = *reinterpret_cast<const float4*>(xbase + (size_t)r * COLS + k0 + c4);
        float4 xv1 = *reinterpret_cast<const float4*>(xbase + (size_t)(r + 32) * COLS + k0 + c4);
        *reinterpret_cast<float4*>(Xs + r * XS_LD + c4) = xv0;
        *reinterpret_cast<float4*>(Xs + (r + 32) * XS_LD + c4) = xv1;
        float4 wv0 = *reinterpret_cast<const float4*>(Wm + (size_t)(o0 + r) * K_DIM + k0 + c4);
        float4 wv1 = *reinterpret_cast<const float4*>(Wm + (size_t)(o0 + r + 32) * K_DIM + k0 + c4);
        *reinterpret_cast<float4*>(Ws + r * XS_LD + c4) = wv0;
        *reinterpret_cast<float4*>(Ws + (r + 32) * XS_LD + c4) = wv1;
        __syncthreads();
#pragma unroll 4
        for (int kk = 0; kk < KC; ++kk) {
            double xa[4], wb[4];
#pragma unroll
            for (int i = 0; i < 4; ++i) xa[i] = (double)Xs[(4 * ty + i) * XS_LD + kk];
#pragma unroll
            for (int j = 0; j < 4; ++j) wb[j] = (double)Ws[(4 * tx + j) * XS_LD + kk];
#pragma unroll
            for (int i = 0; i < 4; ++i)
#pragma unroll
                for (int j = 0; j < 4; ++j) acc[i][j] = fma(xa[i], wb[j], acc[i][j]);
        }
    }
    __syncthreads();
#pragma unroll
    for (int i = 0; i < 4; ++i)
#pragma unroll
        for (int j = 0; j < 4; ++j) sd[(4 * ty + i) * SC_LD + (4 * tx + j)] = acc[i][j];
    __syncthreads();
    if (tid < TILE) {
        double v = 0.0;
        float* outp = out + (size_t)b * F_DIM + o0 + tid;
        for (int t = 0; t < T_DIM; ++t) {
            double cu = sd[t * SC_LD + tid];
            double h = v + (cu - v) * 0.5;
            bool s = (h >= 1.0);
            outp[(size_t)t * COLS] = s ? 1.0f : 0.0f;
            v = s ? 0.0 : h;
        }
    }
}

// ------------------------------------------------------------------- launch
extern "C" void kernel_launch(void* const* d_in, const int* in_sizes, int n_in,
                              void* d_out, int out_size, void* d_ws, size_t ws_size,
                              hipStream_t stream) {
    const float* x = (const float*)d_in[0];   // [64][256][1024]
    const float* Wm = (const float*)d_in[1];  // [1024][1024]
    float* out = (float*)d_out;

    const size_t OFF_A  = 0;                                  // 64 MB
    const size_t OFF_B  = OFF_A + (size_t)M_DIM * KP * 2;     // 4 MB
    const size_t NEEDED = OFF_B + (size_t)F_DIM * KP * 2;

    if (ws_size < NEEDED) {
        dim3 grid(F_DIM / TILE, B_DIM, 1);
        lif_fused_kernel<<<grid, dim3(256), 0, stream>>>(x, Wm, out);
        return;
    }

    unsigned char* ws = (unsigned char*)d_ws;
    unsigned short* Abuf = (unsigned short*)(ws + OFF_A);
    unsigned short* Bbuf = (unsigned short*)(ws + OFF_B);

    split_kernel<<<dim3(16384 + 1024), dim3(256), 0, stream>>>(x, Wm, Abuf, Bbuf);
    gemm_scan_kernel<<<dim3(512), dim3(256), 0, stream>>>(Abuf, Bbuf, x, Wm, out);
}

// Round 7
// 247.888 us; speedup vs baseline: 1.1324x; 1.1009x over previous
//
#include <hip/hip_runtime.h>

// LinearLIFBlock: cur = X[16384x1024] * W^T[1024x1024]; LIF scan over t (64 steps).
// R7: R4's proven BK=32 2-barrier K-loop + R5's proven XOR swizzle (0 bank
// conflicts) + separate grid-strided fp64 fixup (R6's fused tail caused block
// stragglers). Margin 6e-5 (>12 sigma of ~4e-6 rms cur error) cuts fixup
// traffic ~2.5x. 128x256 tile, grid=512 (2 blocks/CU), wave 64x128, A rows
// remapped to (b*64+t), in-register LIF shfl relay (validated R3/R4).

#define T_DIM 64
#define B_DIM 256
#define F_DIM 1024
#define K_DIM 1024
#define M_DIM 16384            // T*B
#define COLS  (B_DIM * F_DIM)  // 262144 scan columns
#define KP    2048             // packed K: [hi | lo]
#define MARGIN 6e-5f
#define LIST_CAP 32768

typedef __attribute__((ext_vector_type(8))) short short8;
typedef __attribute__((ext_vector_type(4))) float floatx4;

#define ASYNC_CP16(gp, lp)                                                     \
    __builtin_amdgcn_global_load_lds(                                          \
        (const __attribute__((address_space(1))) unsigned int*)(gp),           \
        (__attribute__((address_space(3))) unsigned int*)(lp), 16, 0, 0)

// ---------------------------------------------------------------- bf16 split
__device__ inline unsigned short f32_to_bf16_rne(float f) {
    unsigned int u = __builtin_bit_cast(unsigned int, f);
    unsigned int r = (u + 0x7FFFu + ((u >> 16) & 1u)) >> 16;
    return (unsigned short)r;
}
__device__ inline float bf16_to_f32(unsigned short h) {
    unsigned int u = ((unsigned int)h) << 16;
    return __builtin_bit_cast(float, u);
}

// Fused split: blocks [0,16384) do X (+row remap to b*64+t), [16384,17408) do W.
// Also zeroes the fixup counter (blk 0).
__global__ __launch_bounds__(256) void split_kernel(
    const float* __restrict__ x, const float* __restrict__ Wm,
    unsigned short* __restrict__ A, unsigned short* __restrict__ B,
    unsigned int* __restrict__ counter)
{
    if (blockIdx.x == 0 && threadIdx.x == 0) *counter = 0;
    const int blk = blockIdx.x;
    const float* in;
    unsigned short* dst;
    int g;
    int orow;
    if (blk < 16384) {
        g = blk * 256 + threadIdx.x;          // float4 index into x
        int e = g * 4;
        int row = e >> 10;                    // t*256 + b
        orow = ((row & 255) << 6) | (row >> 8);  // b*64 + t
        in = x; dst = A;
    } else {
        g = (blk - 16384) * 256 + threadIdx.x;
        int e = g * 4;
        orow = e >> 10;                       // o
        in = Wm; dst = B;
    }
    int k = (g * 4) & 1023;
    float4 v = reinterpret_cast<const float4*>(in)[g];
    ushort4 h, l;
    float f;
    f = v.x; h.x = f32_to_bf16_rne(f); l.x = f32_to_bf16_rne(f - bf16_to_f32(h.x));
    f = v.y; h.y = f32_to_bf16_rne(f); l.y = f32_to_bf16_rne(f - bf16_to_f32(h.y));
    f = v.z; h.z = f32_to_bf16_rne(f); l.z = f32_to_bf16_rne(f - bf16_to_f32(h.z));
    f = v.w; h.w = f32_to_bf16_rne(f); l.w = f32_to_bf16_rne(f - bf16_to_f32(h.w));
    reinterpret_cast<ushort4*>(dst)[(size_t)orow * (KP / 4) + (k >> 2)] = h;
    reinterpret_cast<ushort4*>(dst)[(size_t)orow * (KP / 4) + 256 + (k >> 2)] = l;
}

// ----------------------------------------------- fused MFMA GEMM + LIF scan
// Block tile 128(M) x 256(N); effective K=3072:
//   seg0 = A.hi*B.hi, seg1 = A.lo*B.hi, seg2 = A.hi*B.lo
__global__ __launch_bounds__(256, 2) void gemm_scan_kernel(
    const unsigned short* __restrict__ A,  // [16384][2048], rows b*64+t
    const unsigned short* __restrict__ B,  // [1024][2048],  rows o
    float* __restrict__ out,
    unsigned int* __restrict__ counter, unsigned int* __restrict__ list)
{
    __shared__ unsigned short As[128 * 32];  // 8 KB
    __shared__ unsigned short Bs[256 * 32];  // 16 KB

    const int tid  = threadIdx.x;
    const int lane = tid & 63;
    const int wv   = tid >> 6;
    // XCD-aware: XCD = lid&7 owns a contiguous 16-mt stripe; nt varies fastest.
    const int lid = blockIdx.x;                      // 0..511
    const int mt  = ((lid & 7) << 4) | (lid >> 5);   // 0..127
    const int nt  = (lid >> 3) & 3;                  // 0..3
    const int m0  = mt * 128;
    const int n0  = nt * 256;
    const int wm  = (wv & 1) * 64;
    const int wn  = (wv >> 1) * 128;

    floatx4 acc[4][8] = {};

    // Staging with source-side XOR chunk swizzle (R5-validated: 0 conflicts).
    // LDS slot (row, c) holds global chunk c ^ ((row>>1)&3).
    const int srow = tid >> 2;                      // 0..63 staging row
    const int slin = (tid & 3) * 8;                 // linear LDS chunk (dest)
    const int ssw  = (((tid & 3) ^ ((tid >> 3) & 3)) * 8);  // swizzled source chunk
    const int lrow = lane & 15;
    const int q    = lane >> 4;                     // 0..3
    const int rsw  = (lrow >> 1) & 3;               // read-side swizzle key

    const unsigned short* Ab = A + (size_t)m0 * KP;
    const unsigned short* Bb = B + (size_t)n0 * KP;

    for (int k0 = 0; k0 < 3072; k0 += 32) {
        const int aoff = (k0 < 2048) ? k0 : k0 - 2048;  // seg2 replays hi
        const int boff = (k0 < 1024) ? k0 : k0 - 1024;  // seg1/2 replay hi
        __syncthreads();
        ASYNC_CP16(Ab + (size_t)srow * KP + aoff + ssw,         As + srow * 32 + slin);
        ASYNC_CP16(Ab + (size_t)(srow + 64) * KP + aoff + ssw,  As + (srow + 64) * 32 + slin);
        ASYNC_CP16(Bb + (size_t)srow * KP + boff + ssw,         Bs + srow * 32 + slin);
        ASYNC_CP16(Bb + (size_t)(srow + 64) * KP + boff + ssw,  Bs + (srow + 64) * 32 + slin);
        ASYNC_CP16(Bb + (size_t)(srow + 128) * KP + boff + ssw, Bs + (srow + 128) * 32 + slin);
        ASYNC_CP16(Bb + (size_t)(srow + 192) * KP + boff + ssw, Bs + (srow + 192) * 32 + slin);
        __syncthreads();

        const int sl = (q ^ rsw) * 8;
        short8 a[4], b[8];
#pragma unroll
        for (int i = 0; i < 4; ++i)
            a[i] = *reinterpret_cast<const short8*>(&As[(wm + i * 16 + lrow) * 32 + sl]);
#pragma unroll
        for (int j = 0; j < 8; ++j)
            b[j] = *reinterpret_cast<const short8*>(&Bs[(wn + j * 16 + lrow) * 32 + sl]);
#pragma unroll
        for (int i = 0; i < 4; ++i)
#pragma unroll
            for (int j = 0; j < 8; ++j)
                acc[i][j] = __builtin_amdgcn_mfma_f32_16x16x32_bf16(a[i], b[j], acc[i][j], 0, 0, 0);
    }

    // ---- fused LIF scan in registers (validated relay) ----
    // Wave owns all 64 t of batch b = mt*2 + (wv&1), cols o = n0+wn+j*16+col.
    // acc[i][j][r] = cur at t = i*16 + q*4 + r, col = lane&15.
    const int col = lane & 15;
    const int b_g = mt * 2 + (wv & 1);

    unsigned int fmask = 0;
#pragma unroll
    for (int j = 0; j < 8; ++j) {
        float v = 0.f;
        bool fl = false;
#pragma unroll
        for (int i = 0; i < 4; ++i) {
#pragma unroll
            for (int qq = 0; qq < 4; ++qq) {
                if (q == qq) {
#pragma unroll
                    for (int r = 0; r < 4; ++r) {
                        float cu = acc[i][j][r];
                        float h = v + (cu - v) * 0.5f;
                        float d = h - 1.0f;
                        bool sp = (d >= 0.f);
                        fl |= (fabsf(d) < MARGIN);
                        acc[i][j][r] = sp ? 1.0f : 0.0f;  // spike overwrites cur
                        v = sp ? 0.f : h;
                    }
                }
                v = __shfl(v, qq * 16 + col, 64);  // broadcast owner's v
            }
        }
        if (fl) fmask |= (1u << j);
    }
    fmask |= __shfl_xor(fmask, 16, 64);
    fmask |= __shfl_xor(fmask, 32, 64);

    // spike stores
    float* outp = out + (size_t)b_g * F_DIM;
#pragma unroll
    for (int i = 0; i < 4; ++i)
#pragma unroll
        for (int j = 0; j < 8; ++j)
#pragma unroll
            for (int r = 0; r < 4; ++r) {
                int t = i * 16 + q * 4 + r;
                int o = n0 + wn + j * 16 + col;
                outp[(size_t)t * COLS + o] = acc[i][j][r];
            }

    if (q == 0 && fmask) {
        for (int j = 0; j < 8; ++j)
            if (fmask & (1u << j)) {
                unsigned int idx = atomicAdd(counter, 1u);
                if (idx < LIST_CAP)
                    list[idx] = (unsigned int)((b_g << 10) | (n0 + wn + j * 16 + col));
            }
    }
}

// ------------------------------------------------------- exact fp64 fixup
__global__ __launch_bounds__(256) void fixup_kernel(
    const float* __restrict__ x, const float* __restrict__ W,
    const unsigned int* __restrict__ counter, const unsigned int* __restrict__ list,
    float* __restrict__ out)
{
    __shared__ double curd[T_DIM];
    __shared__ float wrow[K_DIM];
    unsigned int n = *counter;
    if (n > LIST_CAP) n = LIST_CAP;
    const int wv = threadIdx.x >> 6, lane = threadIdx.x & 63;

    for (unsigned int idx = blockIdx.x; idx < n; idx += gridDim.x) {
        const unsigned int c = list[idx];
        const int b = c >> 10, o = c & 1023;
        __syncthreads();
        for (int k = threadIdx.x; k < K_DIM; k += 256) wrow[k] = W[(size_t)o * K_DIM + k];
        __syncthreads();
        for (int it = 0; it < 16; ++it) {
            const int t = it * 4 + wv;
            const float* xp = x + (size_t)t * COLS + (size_t)b * F_DIM + lane * 16;
            double s = 0.0;
#pragma unroll
            for (int qq = 0; qq < 4; ++qq) {
                float4 xv = reinterpret_cast<const float4*>(xp)[qq];
                float4 wq = *reinterpret_cast<const float4*>(&wrow[lane * 16 + qq * 4]);
                s += (double)xv.x * (double)wq.x + (double)xv.y * (double)wq.y +
                     (double)xv.z * (double)wq.z + (double)xv.w * (double)wq.w;
            }
#pragma unroll
            for (int off = 32; off > 0; off >>= 1) s += __shfl_down(s, off, 64);
            if (lane == 0) curd[t] = s;
        }
        __syncthreads();
        if (threadIdx.x == 0) {
            double v = 0.0;
            for (int t = 0; t < T_DIM; ++t) {
                double h = v + (curd[t] - v) * 0.5;
                bool s = (h >= 1.0);
                out[(size_t)t * COLS + c] = s ? 1.0f : 0.0f;
                v = s ? 0.0 : h;
            }
        }
        __syncthreads();
    }
}

// --------------------------------------------------- fp64 fallback (round-1)
#define TILE 64
#define KC 32
#define XS_LD 36
#define SC_LD 65

__global__ __launch_bounds__(256) void lif_fused_kernel(
    const float* __restrict__ x, const float* __restrict__ Wm, float* __restrict__ out)
{
    __shared__ __align__(16) unsigned char smem_raw[TILE * SC_LD * sizeof(double)];
    float* sf = reinterpret_cast<float*>(smem_raw);
    double* sd = reinterpret_cast<double*>(smem_raw);
    float* Xs = sf;
    float* Ws = sf + TILE * XS_LD;

    const int b = blockIdx.y;
    const int o0 = blockIdx.x * TILE;
    const int tid = threadIdx.x;
    const int tx = tid & 15, ty = tid >> 4;

    double acc[4][4];
#pragma unroll
    for (int i = 0; i < 4; ++i)
#pragma unroll
        for (int j = 0; j < 4; ++j) acc[i][j] = 0.0;

    const int r = tid >> 3, c4 = (tid & 7) * 4;
    const float* xbase = x + (size_t)b * F_DIM;

    for (int k0 = 0; k0 < K_DIM; k0 += KC) {
        __syncthreads();
        float4 xv0 = *reinterpret_cast<const float4*>(xbase + (size_t)r * COLS + k0 + c4);
        float4 xv1 = *reinterpret_cast<const float4*>(xbase + (size_t)(r + 32) * COLS + k0 + c4);
        *reinterpret_cast<float4*>(Xs + r * XS_LD + c4) = xv0;
        *reinterpret_cast<float4*>(Xs + (r + 32) * XS_LD + c4) = xv1;
        float4 wv0 = *reinterpret_cast<const float4*>(Wm + (size_t)(o0 + r) * K_DIM + k0 + c4);
        float4 wv1 = *reinterpret_cast<const float4*>(Wm + (size_t)(o0 + r + 32) * K_DIM + k0 + c4);
        *reinterpret_cast<float4*>(Ws + r * XS_LD + c4) = wv0;
        *reinterpret_cast<float4*>(Ws + (r + 32) * XS_LD + c4) = wv1;
        __syncthreads();
#pragma unroll 4
        for (int kk = 0; kk < KC; ++kk) {
            double xa[4], wb[4];
#pragma unroll
            for (int i = 0; i < 4; ++i) xa[i] = (double)Xs[(4 * ty + i) * XS_LD + kk];
#pragma unroll
            for (int j = 0; j < 4; ++j) wb[j] = (double)Ws[(4 * tx + j) * XS_LD + kk];
#pragma unroll
            for (int i = 0; i < 4; ++i)
#pragma unroll
                for (int j = 0; j < 4; ++j) acc[i][j] = fma(xa[i], wb[j], acc[i][j]);
        }
    }
    __syncthreads();
#pragma unroll
    for (int i = 0; i < 4; ++i)
#pragma unroll
        for (int j = 0; j < 4; ++j) sd[(4 * ty + i) * SC_LD + (4 * tx + j)] = acc[i][j];
    __syncthreads();
    if (tid < TILE) {
        double v = 0.0;
        float* outp = out + (size_t)b * F_DIM + o0 + tid;
        for (int t = 0; t < T_DIM; ++t) {
            double cu = sd[t * SC_LD + tid];
            double h = v + (cu - v) * 0.5;
            bool s = (h >= 1.0);
            outp[(size_t)t * COLS] = s ? 1.0f : 0.0f;
            v = s ? 0.0 : h;
        }
    }
}

// ------------------------------------------------------------------- launch
extern "C" void kernel_launch(void* const* d_in, const int* in_sizes, int n_in,
                              void* d_out, int out_size, void* d_ws, size_t ws_size,
                              hipStream_t stream) {
    const float* x = (const float*)d_in[0];   // [64][256][1024]
    const float* Wm = (const float*)d_in[1];  // [1024][1024]
    float* out = (float*)d_out;

    const size_t OFF_A   = 0;                                   // 64 MB
    const size_t OFF_B   = OFF_A + (size_t)M_DIM * KP * 2;      // 4 MB
    const size_t OFF_CNT = OFF_B + (size_t)F_DIM * KP * 2;
    const size_t OFF_LST = OFF_CNT + 256;
    const size_t NEEDED  = OFF_LST + (size_t)LIST_CAP * 4;

    if (ws_size < NEEDED) {
        dim3 grid(F_DIM / TILE, B_DIM, 1);
        lif_fused_kernel<<<grid, dim3(256), 0, stream>>>(x, Wm, out);
        return;
    }

    unsigned char* ws = (unsigned char*)d_ws;
    unsigned short* Abuf = (unsigned short*)(ws + OFF_A);
    unsigned short* Bbuf = (unsigned short*)(ws + OFF_B);
    unsigned int* counter = (unsigned int*)(ws + OFF_CNT);
    unsigned int* list = (unsigned int*)(ws + OFF_LST);

    split_kernel<<<dim3(16384 + 1024), dim3(256), 0, stream>>>(x, Wm, Abuf, Bbuf, counter);
    gemm_scan_kernel<<<dim3(512), dim3(256), 0, stream>>>(Abuf, Bbuf, out, counter, list);
    fixup_kernel<<<dim3(512), dim3(256), 0, stream>>>(x, Wm, counter, list, out);
}

// Round 9
// 225.885 us; speedup vs baseline: 1.2427x; 1.0974x over previous
//
#include <hip/hip_runtime.h>

// LinearLIFBlock: cur = X[16384x1024] * W^T[1024x1024]; LIF scan over t (64 steps).
// R9: single-pass K=1024 GEMM: stage A_hi/A_lo/B_hi/B_lo tiles together (48 KB)
// and issue all three split products (ah*bh + al*bh + ah*bl = 96 MFMA) per
// k-tile. 3x fewer barrier drains (32 vs 96), LDS reads/FLOP 36->24, staged
// bytes 6->4 per elem. XOR swizzle (0 conflicts, R5/R7-validated), 128x256
// tile, grid=512 (2 blocks/CU), wave 64x128, A rows (b*64+t), in-register LIF
// shfl relay. Plain stream launches (R8's cooperative launch failed in this
// harness). Margin 6e-5 flagged columns get exact fp64 fixup.

#define T_DIM 64
#define B_DIM 256
#define F_DIM 1024
#define K_DIM 1024
#define M_DIM 16384            // T*B
#define COLS  (B_DIM * F_DIM)  // 262144 scan columns
#define KP    2048             // packed K: [hi | lo]
#define MARGIN 6e-5f
#define LIST_CAP 32768

typedef __attribute__((ext_vector_type(8))) short short8;
typedef __attribute__((ext_vector_type(4))) float floatx4;

#define ASYNC_CP16(gp, lp)                                                     \
    __builtin_amdgcn_global_load_lds(                                          \
        (const __attribute__((address_space(1))) unsigned int*)(gp),           \
        (__attribute__((address_space(3))) unsigned int*)(lp), 16, 0, 0)

// ---------------------------------------------------------------- bf16 split
__device__ inline unsigned short f32_to_bf16_rne(float f) {
    unsigned int u = __builtin_bit_cast(unsigned int, f);
    unsigned int r = (u + 0x7FFFu + ((u >> 16) & 1u)) >> 16;
    return (unsigned short)r;
}
__device__ inline float bf16_to_f32(unsigned short h) {
    unsigned int u = ((unsigned int)h) << 16;
    return __builtin_bit_cast(float, u);
}

// Fused split: blocks [0,16384) do X (+row remap to b*64+t), [16384,17408) do W.
// Also zeroes the fixup counter (blk 0).
__global__ __launch_bounds__(256) void split_kernel(
    const float* __restrict__ x, const float* __restrict__ Wm,
    unsigned short* __restrict__ A, unsigned short* __restrict__ B,
    unsigned int* __restrict__ counter)
{
    if (blockIdx.x == 0 && threadIdx.x == 0) *counter = 0;
    const int blk = blockIdx.x;
    const float* in;
    unsigned short* dst;
    int g;
    int orow;
    if (blk < 16384) {
        g = blk * 256 + threadIdx.x;          // float4 index into x
        int e = g * 4;
        int row = e >> 10;                    // t*256 + b
        orow = ((row & 255) << 6) | (row >> 8);  // b*64 + t
        in = x; dst = A;
    } else {
        g = (blk - 16384) * 256 + threadIdx.x;
        int e = g * 4;
        orow = e >> 10;                       // o
        in = Wm; dst = B;
    }
    int k = (g * 4) & 1023;
    float4 v = reinterpret_cast<const float4*>(in)[g];
    ushort4 h, l;
    float f;
    f = v.x; h.x = f32_to_bf16_rne(f); l.x = f32_to_bf16_rne(f - bf16_to_f32(h.x));
    f = v.y; h.y = f32_to_bf16_rne(f); l.y = f32_to_bf16_rne(f - bf16_to_f32(h.y));
    f = v.z; h.z = f32_to_bf16_rne(f); l.z = f32_to_bf16_rne(f - bf16_to_f32(h.z));
    f = v.w; h.w = f32_to_bf16_rne(f); l.w = f32_to_bf16_rne(f - bf16_to_f32(h.w));
    reinterpret_cast<ushort4*>(dst)[(size_t)orow * (KP / 4) + (k >> 2)] = h;
    reinterpret_cast<ushort4*>(dst)[(size_t)orow * (KP / 4) + 256 + (k >> 2)] = l;
}

// ----------------------------------------------- fused MFMA GEMM + LIF scan
// Block tile 128(M) x 256(N); single K=1024 pass, 3 products per k-tile:
//   cur = A.hi*B.hi + A.lo*B.hi + A.hi*B.lo
__global__ __launch_bounds__(256, 2) void gemm_scan_kernel(
    const unsigned short* __restrict__ A,  // [16384][2048], rows b*64+t
    const unsigned short* __restrict__ B,  // [1024][2048],  rows o
    float* __restrict__ out,
    unsigned int* __restrict__ counter, unsigned int* __restrict__ list)
{
    __shared__ unsigned short Ah[128 * 32];  // 8 KB
    __shared__ unsigned short Al[128 * 32];  // 8 KB
    __shared__ unsigned short Bh[256 * 32];  // 16 KB
    __shared__ unsigned short Bl[256 * 32];  // 16 KB

    const int tid  = threadIdx.x;
    const int lane = tid & 63;
    const int wv   = tid >> 6;
    // XCD-aware: XCD = lid&7 owns a contiguous 16-mt stripe; nt varies fastest.
    const int lid = blockIdx.x;                      // 0..511
    const int mt  = ((lid & 7) << 4) | (lid >> 5);   // 0..127
    const int nt  = (lid >> 3) & 3;                  // 0..3
    const int m0  = mt * 128;
    const int n0  = nt * 256;
    const int wm  = (wv & 1) * 64;
    const int wn  = (wv >> 1) * 128;

    floatx4 acc[4][8] = {};

    // Staging with source-side XOR chunk swizzle (R5/R7-validated: 0 conflicts).
    const int srow = tid >> 2;                      // 0..63 staging row
    const int slin = (tid & 3) * 8;                 // linear LDS chunk (dest)
    const int ssw  = (((tid & 3) ^ ((tid >> 3) & 3)) * 8);  // swizzled source chunk
    const int lrow = lane & 15;
    const int q    = lane >> 4;                     // 0..3
    const int rsw  = (lrow >> 1) & 3;               // read-side swizzle key

    const unsigned short* Ab = A + (size_t)m0 * KP;
    const unsigned short* Bb = B + (size_t)n0 * KP;

    for (int k0 = 0; k0 < 1024; k0 += 32) {
        __syncthreads();
        // A hi/lo: 2 insts each; B hi/lo: 4 insts each. 12 total / thread.
        ASYNC_CP16(Ab + (size_t)srow * KP + k0 + ssw,                Ah + srow * 32 + slin);
        ASYNC_CP16(Ab + (size_t)(srow + 64) * KP + k0 + ssw,         Ah + (srow + 64) * 32 + slin);
        ASYNC_CP16(Ab + (size_t)srow * KP + 1024 + k0 + ssw,         Al + srow * 32 + slin);
        ASYNC_CP16(Ab + (size_t)(srow + 64) * KP + 1024 + k0 + ssw,  Al + (srow + 64) * 32 + slin);
        ASYNC_CP16(Bb + (size_t)srow * KP + k0 + ssw,                Bh + srow * 32 + slin);
        ASYNC_CP16(Bb + (size_t)(srow + 64) * KP + k0 + ssw,         Bh + (srow + 64) * 32 + slin);
        ASYNC_CP16(Bb + (size_t)(srow + 128) * KP + k0 + ssw,        Bh + (srow + 128) * 32 + slin);
        ASYNC_CP16(Bb + (size_t)(srow + 192) * KP + k0 + ssw,        Bh + (srow + 192) * 32 + slin);
        ASYNC_CP16(Bb + (size_t)srow * KP + 1024 + k0 + ssw,         Bl + srow * 32 + slin);
        ASYNC_CP16(Bb + (size_t)(srow + 64) * KP + 1024 + k0 + ssw,  Bl + (srow + 64) * 32 + slin);
        ASYNC_CP16(Bb + (size_t)(srow + 128) * KP + 1024 + k0 + ssw, Bl + (srow + 128) * 32 + slin);
        ASYNC_CP16(Bb + (size_t)(srow + 192) * KP + 1024 + k0 + ssw, Bl + (srow + 192) * 32 + slin);
        __syncthreads();

        const int sl = (q ^ rsw) * 8;
        short8 ah[4], al[4];
#pragma unroll
        for (int i = 0; i < 4; ++i) {
            ah[i] = *reinterpret_cast<const short8*>(&Ah[(wm + i * 16 + lrow) * 32 + sl]);
            al[i] = *reinterpret_cast<const short8*>(&Al[(wm + i * 16 + lrow) * 32 + sl]);
        }
        // j in two halves of 4 to cap live VGPRs (~210 incl. 128 acc)
#pragma unroll
        for (int jh = 0; jh < 2; ++jh) {
            short8 bh[4], bl[4];
#pragma unroll
            for (int j4 = 0; j4 < 4; ++j4) {
                const int jr = (wn + (jh * 4 + j4) * 16 + lrow) * 32 + sl;
                bh[j4] = *reinterpret_cast<const short8*>(&Bh[jr]);
                bl[j4] = *reinterpret_cast<const short8*>(&Bl[jr]);
            }
#pragma unroll
            for (int i = 0; i < 4; ++i)
#pragma unroll
                for (int j4 = 0; j4 < 4; ++j4)
                    acc[i][jh * 4 + j4] = __builtin_amdgcn_mfma_f32_16x16x32_bf16(
                        ah[i], bh[j4], acc[i][jh * 4 + j4], 0, 0, 0);
#pragma unroll
            for (int i = 0; i < 4; ++i)
#pragma unroll
                for (int j4 = 0; j4 < 4; ++j4)
                    acc[i][jh * 4 + j4] = __builtin_amdgcn_mfma_f32_16x16x32_bf16(
                        al[i], bh[j4], acc[i][jh * 4 + j4], 0, 0, 0);
#pragma unroll
            for (int i = 0; i < 4; ++i)
#pragma unroll
                for (int j4 = 0; j4 < 4; ++j4)
                    acc[i][jh * 4 + j4] = __builtin_amdgcn_mfma_f32_16x16x32_bf16(
                        ah[i], bl[j4], acc[i][jh * 4 + j4], 0, 0, 0);
        }
    }

    // ---- fused LIF scan in registers (validated relay) ----
    // Wave owns all 64 t of batch b = mt*2 + (wv&1), cols o = n0+wn+j*16+col.
    // acc[i][j][r] = cur at t = i*16 + q*4 + r, col = lane&15.
    const int col = lane & 15;
    const int b_g = mt * 2 + (wv & 1);

    unsigned int fmask = 0;
#pragma unroll
    for (int j = 0; j < 8; ++j) {
        float v = 0.f;
        bool fl = false;
#pragma unroll
        for (int i = 0; i < 4; ++i) {
#pragma unroll
            for (int qq = 0; qq < 4; ++qq) {
                if (q == qq) {
#pragma unroll
                    for (int r = 0; r < 4; ++r) {
                        float cu = acc[i][j][r];
                        float h = v + (cu - v) * 0.5f;
                        float d = h - 1.0f;
                        bool sp = (d >= 0.f);
                        fl |= (fabsf(d) < MARGIN);
                        acc[i][j][r] = sp ? 1.0f : 0.0f;  // spike overwrites cur
                        v = sp ? 0.f : h;
                    }
                }
                v = __shfl(v, qq * 16 + col, 64);  // broadcast owner's v
            }
        }
        if (fl) fmask |= (1u << j);
    }
    fmask |= __shfl_xor(fmask, 16, 64);
    fmask |= __shfl_xor(fmask, 32, 64);

    // spike stores
    float* outp = out + (size_t)b_g * F_DIM;
#pragma unroll
    for (int i = 0; i < 4; ++i)
#pragma unroll
        for (int j = 0; j < 8; ++j)
#pragma unroll
            for (int r = 0; r < 4; ++r) {
                int t = i * 16 + q * 4 + r;
                int o = n0 + wn + j * 16 + col;
                outp[(size_t)t * COLS + o] = acc[i][j][r];
            }

    if (q == 0 && fmask) {
        for (int j = 0; j < 8; ++j)
            if (fmask & (1u << j)) {
                unsigned int idx = atomicAdd(counter, 1u);
                if (idx < LIST_CAP)
                    list[idx] = (unsigned int)((b_g << 10) | (n0 + wn + j * 16 + col));
            }
    }
}

// ------------------------------------------------------- exact fp64 fixup
__global__ __launch_bounds__(256) void fixup_kernel(
    const float* __restrict__ x, const float* __restrict__ W,
    const unsigned int* __restrict__ counter, const unsigned int* __restrict__ list,
    float* __restrict__ out)
{
    __shared__ double curd[T_DIM];
    __shared__ float wrow[K_DIM];
    unsigned int n = *counter;
    if (n > LIST_CAP) n = LIST_CAP;
    const int wv = threadIdx.x >> 6, lane = threadIdx.x & 63;

    for (unsigned int idx = blockIdx.x; idx < n; idx += gridDim.x) {
        const unsigned int c = list[idx];
        const int b = c >> 10, o = c & 1023;
        __syncthreads();
        for (int k = threadIdx.x; k < K_DIM; k += 256) wrow[k] = W[(size_t)o * K_DIM + k];
        __syncthreads();
        for (int it = 0; it < 16; ++it) {
            const int t = it * 4 + wv;
            const float* xp = x + (size_t)t * COLS + (size_t)b * F_DIM + lane * 16;
            double s = 0.0;
#pragma unroll
            for (int qq = 0; qq < 4; ++qq) {
                float4 xv = reinterpret_cast<const float4*>(xp)[qq];
                float4 wq = *reinterpret_cast<const float4*>(&wrow[lane * 16 + qq * 4]);
                s += (double)xv.x * (double)wq.x + (double)xv.y * (double)wq.y +
                     (double)xv.z * (double)wq.z + (double)xv.w * (double)wq.w;
            }
#pragma unroll
            for (int off = 32; off > 0; off >>= 1) s += __shfl_down(s, off, 64);
            if (lane == 0) curd[t] = s;
        }
        __syncthreads();
        if (threadIdx.x == 0) {
            double v = 0.0;
            for (int t = 0; t < T_DIM; ++t) {
                double h = v + (curd[t] - v) * 0.5;
                bool s = (h >= 1.0);
                out[(size_t)t * COLS + c] = s ? 1.0f : 0.0f;
                v = s ? 0.0 : h;
            }
        }
        __syncthreads();
    }
}

// --------------------------------------------------- fp64 fallback (round-1)
#define TILE 64
#define KC 32
#define XS_LD 36
#define SC_LD 65

__global__ __launch_bounds__(256) void lif_fused_kernel(
    const float* __restrict__ x, const float* __restrict__ Wm, float* __restrict__ out)
{
    __shared__ __align__(16) unsigned char smem_raw[TILE * SC_LD * sizeof(double)];
    float* sf = reinterpret_cast<float*>(smem_raw);
    double* sd = reinterpret_cast<double*>(smem_raw);
    float* Xs = sf;
    float* Ws = sf + TILE * XS_LD;

    const int b = blockIdx.y;
    const int o0 = blockIdx.x * TILE;
    const int tid = threadIdx.x;
    const int tx = tid & 15, ty = tid >> 4;

    double acc[4][4];
#pragma unroll
    for (int i = 0; i < 4; ++i)
#pragma unroll
        for (int j = 0; j < 4; ++j) acc[i][j] = 0.0;

    const int r = tid >> 3, c4 = (tid & 7) * 4;
    const float* xbase = x + (size_t)b * F_DIM;

    for (int k0 = 0; k0 < K_DIM; k0 += KC) {
        __syncthreads();
        float4 xv0 = *reinterpret_cast<const float4*>(xbase + (size_t)r * COLS + k0 + c4);
        float4 xv1 = *reinterpret_cast<const float4*>(xbase + (size_t)(r + 32) * COLS + k0 + c4);
        *reinterpret_cast<float4*>(Xs + r * XS_LD + c4) = xv0;
        *reinterpret_cast<float4*>(Xs + (r + 32) * XS_LD + c4) = xv1;
        float4 wv0 = *reinterpret_cast<const float4*>(Wm + (size_t)(o0 + r) * K_DIM + k0 + c4);
        float4 wv1 = *reinterpret_cast<const float4*>(Wm + (size_t)(o0 + r + 32) * K_DIM + k0 + c4);
        *reinterpret_cast<float4*>(Ws + r * XS_LD + c4) = wv0;
        *reinterpret_cast<float4*>(Ws + (r + 32) * XS_LD + c4) = wv1;
        __syncthreads();
#pragma unroll 4
        for (int kk = 0; kk < KC; ++kk) {
            double xa[4], wb[4];
#pragma unroll
            for (int i = 0; i < 4; ++i) xa[i] = (double)Xs[(4 * ty + i) * XS_LD + kk];
#pragma unroll
            for (int j = 0; j < 4; ++j) wb[j] = (double)Ws[(4 * tx + j) * XS_LD + kk];
#pragma unroll
            for (int i = 0; i < 4; ++i)
#pragma unroll
                for (int j = 0; j < 4; ++j) acc[i][j] = fma(xa[i], wb[j], acc[i][j]);
        }
    }
    __syncthreads();
#pragma unroll
    for (int i = 0; i < 4; ++i)
#pragma unroll
        for (int j = 0; j < 4; ++j) sd[(4 * ty + i) * SC_LD + (4 * tx + j)] = acc[i][j];
    __syncthreads();
    if (tid < TILE) {
        double v = 0.0;
        float* outp = out + (size_t)b * F_DIM + o0 + tid;
        for (int t = 0; t < T_DIM; ++t) {
            double cu = sd[t * SC_LD + tid];
            double h = v + (cu - v) * 0.5;
            bool s = (h >= 1.0);
            outp[(size_t)t * COLS] = s ? 1.0f : 0.0f;
            v = s ? 0.0 : h;
        }
    }
}

// ------------------------------------------------------------------- launch
extern "C" void kernel_launch(void* const* d_in, const int* in_sizes, int n_in,
                              void* d_out, int out_size, void* d_ws, size_t ws_size,
                              hipStream_t stream) {
    const float* x = (const float*)d_in[0];   // [64][256][1024]
    const float* Wm = (const float*)d_in[1];  // [1024][1024]
    float* out = (float*)d_out;

    const size_t OFF_A   = 0;                                   // 64 MB
    const size_t OFF_B   = OFF_A + (size_t)M_DIM * KP * 2;      // 4 MB
    const size_t OFF_CNT = OFF_B + (size_t)F_DIM * KP * 2;
    const size_t OFF_LST = OFF_CNT + 256;
    const size_t NEEDED  = OFF_LST + (size_t)LIST_CAP * 4;

    if (ws_size < NEEDED) {
        dim3 grid(F_DIM / TILE, B_DIM, 1);
        lif_fused_kernel<<<grid, dim3(256), 0, stream>>>(x, Wm, out);
        return;
    }

    unsigned char* ws = (unsigned char*)d_ws;
    unsigned short* Abuf = (unsigned short*)(ws + OFF_A);
    unsigned short* Bbuf = (unsigned short*)(ws + OFF_B);
    unsigned int* counter = (unsigned int*)(ws + OFF_CNT);
    unsigned int* list = (unsigned int*)(ws + OFF_LST);

    split_kernel<<<dim3(16384 + 1024), dim3(256), 0, stream>>>(x, Wm, Abuf, Bbuf, counter);
    gemm_scan_kernel<<<dim3(512), dim3(256), 0, stream>>>(Abuf, Bbuf, out, counter, list);
    fixup_kernel<<<dim3(512), dim3(256), 0, stream>>>(x, Wm, counter, list, out);
}